// Round 1
// baseline (6615.970 us; speedup 1.0000x reference)
//
#include <hip/hip_runtime.h>

#define NL 50000
#define NS 128
#define G 160
#define GSQ (160*160)
#define GCUBE (160*160*160)

// One wave (64 lanes) per LOR; each lane handles samples lane and lane+64.
// Phase 1: trilinear gather + wave-reduce -> line integral.
// Phase 2: trilinear scatter of KW^2*step^2*integral via atomics.
// s0,s1,s2: strides mapping the (permuted-frame) sample index to the flat
// image/out array. Gather and scatter use the same flat offset for all axes.
__global__ __launch_bounds__(256) void ray_kernel(
    const float* __restrict__ img,
    const float* __restrict__ lors,   // [6][NL] row-major
    float* __restrict__ bp,
    int s0, int s1, int s2)
{
    const int wave = threadIdx.x >> 6;
    const int lane = threadIdx.x & 63;
    const int lor  = blockIdx.x * 4 + wave;

    const float p1x = lors[0*NL + lor];
    const float p1y = lors[1*NL + lor];
    const float p1z = lors[2*NL + lor];
    const float dxv = lors[3*NL + lor] - p1x;
    const float dyv = lors[4*NL + lor] - p1y;
    const float dzv = lors[5*NL + lor] - p1z;
    const float len  = sqrtf(dxv*dxv + dyv*dyv + dzv*dzv);
    const float step = len * (1.0f/NS);

    int   iv[2][3];
    float wv[2][3];
    float sum = 0.0f;

    #pragma unroll
    for (int q = 0; q < 2; ++q) {
        const int s = lane + q*64;
        const float t = ((float)s + 0.5f) * (1.0f/NS);
        const float pos[3] = { p1x + t*dxv, p1y + t*dyv, p1z + t*dzv };
        #pragma unroll
        for (int d = 0; d < 3; ++d) {
            // f = (pos - origin)/vsize - 0.5 ; origin=-100, vsize=1.25
            float f = (pos[d] + 100.0f) / 1.25f - 0.5f;
            f = fminf(fmaxf(f, 0.0f), 159.0f);
            int i = (int)floorf(f);
            i = i > 158 ? 158 : i;
            iv[q][d] = i;
            wv[q][d] = f - (float)i;
        }
        const int base = iv[q][0]*s0 + iv[q][1]*s1 + iv[q][2]*s2;
        const float wx = wv[q][0], wy = wv[q][1], wz = wv[q][2];
        const float v000 = img[base];
        const float v001 = img[base + s2];
        const float v010 = img[base + s1];
        const float v011 = img[base + s1 + s2];
        const float v100 = img[base + s0];
        const float v101 = img[base + s0 + s2];
        const float v110 = img[base + s0 + s1];
        const float v111 = img[base + s0 + s1 + s2];
        const float c00 = v000 + wz*(v001 - v000);
        const float c01 = v010 + wz*(v011 - v010);
        const float c10 = v100 + wz*(v101 - v100);
        const float c11 = v110 + wz*(v111 - v110);
        const float c0  = c00 + wy*(c01 - c00);
        const float c1  = c10 + wy*(c11 - c10);
        sum += c0 + wx*(c1 - c0);
    }

    // 64-lane butterfly reduction
    #pragma unroll
    for (int off = 32; off > 0; off >>= 1)
        sum += __shfl_xor(sum, off, 64);

    const float proj    = 3.0f * step * sum;   // kernel_width * step * val.sum()
    const float contrib = 3.0f * proj * step;  // kernel_width * line_integral * step

    #pragma unroll
    for (int q = 0; q < 2; ++q) {
        const int base = iv[q][0]*s0 + iv[q][1]*s1 + iv[q][2]*s2;
        const float wx = wv[q][0], wy = wv[q][1], wz = wv[q][2];
        const float ux = 1.0f - wx, uy = 1.0f - wy, uz = 1.0f - wz;
        atomicAdd(&bp[base],                contrib*ux*uy*uz);
        atomicAdd(&bp[base + s2],           contrib*ux*uy*wz);
        atomicAdd(&bp[base + s1],           contrib*ux*wy*uz);
        atomicAdd(&bp[base + s1 + s2],      contrib*ux*wy*wz);
        atomicAdd(&bp[base + s0],           contrib*wx*uy*uz);
        atomicAdd(&bp[base + s0 + s2],      contrib*wx*uy*wz);
        atomicAdd(&bp[base + s0 + s1],      contrib*wx*wy*uz);
        atomicAdd(&bp[base + s0 + s1 + s2], contrib*wx*wy*wz);
    }
}

__global__ __launch_bounds__(256) void finalize_kernel(
    const float4* __restrict__ img, const float4* __restrict__ eff,
    float4* __restrict__ out)
{
    const int i = blockIdx.x * 256 + threadIdx.x;
    const float4 a = img[i];
    const float4 e = eff[i];
    float4 o = out[i];
    o.x *= a.x * e.x;
    o.y *= a.y * e.y;
    o.z *= a.z * e.z;
    o.w *= a.w * e.w;
    out[i] = o;
}

extern "C" void kernel_launch(void* const* d_in, const int* in_sizes, int n_in,
                              void* d_out, int out_size, void* d_ws, size_t ws_size,
                              hipStream_t stream) {
    const float* img = (const float*)d_in[0];
    const float* eff = (const float*)d_in[1];
    const float* xl  = (const float*)d_in[2];
    const float* yl  = (const float*)d_in[3];
    const float* zl  = (const float*)d_in[4];
    float* out = (float*)d_out;

    hipMemsetAsync(out, 0, (size_t)out_size * sizeof(float), stream);

    const dim3 blk(256);
    const dim3 grd(NL / 4);   // 4 waves/block, one LOR per wave; 50000/4 exact
    // z-pass: sample idx (i0,i1,i2) -> image[i0,i1,i2]
    ray_kernel<<<grd, blk, 0, stream>>>(img, zl, out, GSQ, G, 1);
    // x-pass: imgx = transpose(img,(2,0,1)) -> image[i1,i2,i0]
    ray_kernel<<<grd, blk, 0, stream>>>(img, xl, out, 1, GSQ, G);
    // y-pass: imgy = transpose(img,(1,0,2)) -> image[i1,i0,i2]
    ray_kernel<<<grd, blk, 0, stream>>>(img, yl, out, G, GSQ, 1);

    finalize_kernel<<<GCUBE/4/256, 256, 0, stream>>>(
        (const float4*)img, (const float4*)eff, (float4*)out);
}